// Round 2
// baseline (311.849 us; speedup 1.0000x reference)
//
#include <hip/hip_runtime.h>
#include <stdint.h>

// ---------------- types ----------------
typedef short shortx8 __attribute__((ext_vector_type(8)));
typedef float floatx4 __attribute__((ext_vector_type(4)));

#define T_LEN 2048
#define BATCH 16
#define DMODEL 512
#define HDIM 512
#define M_ROWS (T_LEN * BATCH)          // 32768
#define NCHUNK 32
#define LCHUNK 64                        // T per chunk
#define NCHAIN (BATCH * HDIM)            // 8192
#define Y_ELEMS (M_ROWS * DMODEL)        // 16777216

// ---------------- helpers ----------------
__device__ __forceinline__ unsigned short f2bf(float f) {
    union { float f; unsigned u; } v; v.f = f;
    unsigned r = (v.u + 0x7FFFu + ((v.u >> 16) & 1u)) >> 16;
    return (unsigned short)r;
}
__device__ __forceinline__ float bf2f(unsigned short u) {
    union { unsigned u; float f; } v; v.u = ((unsigned)u) << 16;
    return v.f;
}

// ---------------- prep: per-channel Lam, Lam^64, gamma ----------------
__global__ void prep_kernel(const float* __restrict__ nu_log, const float* __restrict__ th_log,
                            float* lam_re, float* lam_im, float* l64_re, float* l64_im, float* gam) {
    int h = blockIdx.x * blockDim.x + threadIdx.x;
    if (h >= HDIM) return;
    double nu  = exp((double)nu_log[h]);
    double th  = exp((double)th_log[h]);
    double mag = exp(-nu);
    double lre = mag * cos(th), lim = mag * sin(th);
    double g   = sqrt(1.0 - exp(-2.0 * nu));
    double zr = lre, zi = lim;
    for (int i = 0; i < 6; ++i) { double nr = zr*zr - zi*zi; zi = 2.0*zr*zi; zr = nr; }
    lam_re[h] = (float)lre; lam_im[h] = (float)lim;
    l64_re[h] = (float)zr;  l64_im[h] = (float)zi;
    gam[h] = (float)g;
}

// ---------------- build Bs_wide bf16 (2H x D): rows 0..511 = B_re*gamma, 512..1023 = B_im*gamma
__global__ void conv_B_kernel(const float* __restrict__ B_re, const float* __restrict__ B_im,
                              const float* __restrict__ gam, unsigned short* __restrict__ Bs) {
    int idx = blockIdx.x * blockDim.x + threadIdx.x;     // 0 .. 1024*512-1
    int n = idx >> 9;        // /512
    int d = idx & 511;
    int h = n & 511;
    float v = (n < HDIM ? B_re[h * DMODEL + d] : B_im[h * DMODEL + d]) * gam[h];
    Bs[idx] = f2bf(v);
}

// ---------------- build C2 bf16 (D x 2H): cols 0..511 = C_re, 512..1023 = -C_im
__global__ void conv_C_kernel(const float* __restrict__ C_re, const float* __restrict__ C_im,
                              unsigned short* __restrict__ C2) {
    int idx = blockIdx.x * blockDim.x + threadIdx.x;     // 0 .. 512*1024-1
    int d = idx >> 10;       // /1024
    int k = idx & 1023;
    float v = (k < HDIM) ? C_re[d * HDIM + k] : -C_im[d * HDIM + (k - HDIM)];
    C2[idx] = f2bf(v);
}

// ---------------- cast x fp32 -> bf16 ----------------
__global__ void cast_x_kernel(const float4* __restrict__ x4, unsigned short* __restrict__ xb, int n4) {
    int i = blockIdx.x * blockDim.x + threadIdx.x;
    if (i >= n4) return;
    float4 v = x4[i];
    ushort4 u;
    u.x = f2bf(v.x); u.y = f2bf(v.y); u.z = f2bf(v.z); u.w = f2bf(v.w);
    *(ushort4*)(xb + (size_t)i * 4) = u;
}

// ---------------- NT GEMM, 128x128 tile, bf16 MFMA 16x16x32 ----------------
// A: M x K row-major bf16.  Bmat: N x K row-major bf16.  D[m][n] = sum_k A[m][k]*Bmat[n][k]
// MODE 0: OutB[m*N+n] = bf16(acc)
// MODE 1: OutF[m*N+n] = acc + Dv[n]*Xf[m*N+n]
template <int MODE>
__global__ __launch_bounds__(256) void gemm_nt(const unsigned short* __restrict__ A,
                                               const unsigned short* __restrict__ Bmat,
                                               const int K, const int N,
                                               unsigned short* __restrict__ OutB,
                                               float* __restrict__ OutF,
                                               const float* __restrict__ Dv,
                                               const float* __restrict__ Xf) {
    __shared__ unsigned short As[128 * 32];
    __shared__ unsigned short Bs[128 * 32];
    const int bm = blockIdx.x, bn = blockIdx.y;
    const int tid = threadIdx.x;
    const int wv = tid >> 6, lane = tid & 63;
    const int wr = wv >> 1, wc = wv & 1;
    const int lrow = lane & 15, qq = lane >> 4;
    floatx4 acc[4][4] = {};

    const size_t rowA = (size_t)bm * 128, rowB = (size_t)bn * 128;
    for (int k0 = 0; k0 < K; k0 += 32) {
        // stage 128x32 A tile and B tile via async global->LDS, 16B/lane
        #pragma unroll
        for (int j = 0; j < 2; ++j) {
            int chunk = j * 256 + wv * 64 + lane;          // 0..511
            int r  = chunk >> 2;
            int cc = (chunk & 3) * 8;
            const unsigned short* ga = A    + (rowA + r) * (size_t)K + (k0 + cc);
            const unsigned short* gb = Bmat + (rowB + r) * (size_t)K + (k0 + cc);
            unsigned short* la = As + (size_t)(j * 256 + wv * 64) * 8;   // wave-uniform base
            unsigned short* lb = Bs + (size_t)(j * 256 + wv * 64) * 8;
            __builtin_amdgcn_global_load_lds((const __attribute__((address_space(1))) void*)ga,
                                             (__attribute__((address_space(3))) void*)la, 16, 0, 0);
            __builtin_amdgcn_global_load_lds((const __attribute__((address_space(1))) void*)gb,
                                             (__attribute__((address_space(3))) void*)lb, 16, 0, 0);
        }
        __syncthreads();
        shortx8 af[4], bf[4];
        #pragma unroll
        for (int mi = 0; mi < 4; ++mi)
            af[mi] = *(const shortx8*)&As[(wr * 64 + mi * 16 + lrow) * 32 + qq * 8];
        #pragma unroll
        for (int ni = 0; ni < 4; ++ni)
            bf[ni] = *(const shortx8*)&Bs[(wc * 64 + ni * 16 + lrow) * 32 + qq * 8];
        #pragma unroll
        for (int mi = 0; mi < 4; ++mi)
            #pragma unroll
            for (int ni = 0; ni < 4; ++ni)
                acc[mi][ni] = __builtin_amdgcn_mfma_f32_16x16x32_bf16(af[mi], bf[ni], acc[mi][ni], 0, 0, 0);
        __syncthreads();
    }

    // epilogue: D row = qq*4 + r, col = lrow   (m89/m91-verified C/D mapping)
    #pragma unroll
    for (int mi = 0; mi < 4; ++mi) {
        int mbase = bm * 128 + wr * 64 + mi * 16 + qq * 4;
        #pragma unroll
        for (int ni = 0; ni < 4; ++ni) {
            int n = bn * 128 + wc * 64 + ni * 16 + lrow;
            if (MODE == 0) {
                #pragma unroll
                for (int r = 0; r < 4; ++r)
                    OutB[(size_t)(mbase + r) * N + n] = f2bf(acc[mi][ni][r]);
            } else {
                float dv = Dv[n];
                #pragma unroll
                for (int r = 0; r < 4; ++r) {
                    size_t idx = (size_t)(mbase + r) * N + n;
                    OutF[idx] = acc[mi][ni][r] + dv * Xf[idx];
                }
            }
        }
    }
}

// ---------------- scan pass 1: per-chunk partial (zero init), Bu in bf16 ----------------
__global__ void scan_partial(const unsigned short* __restrict__ Bu,
                             const float* __restrict__ lam_re, const float* __restrict__ lam_im,
                             float* __restrict__ car_re, float* __restrict__ car_im) {
    int gid = blockIdx.x * blockDim.x + threadIdx.x;     // 0 .. 32*8192-1
    int chunk = gid >> 13;
    int c = gid & (NCHAIN - 1);
    int b = c >> 9, h = c & 511;
    float lre = lam_re[h], lim = lam_im[h];
    float vre = 0.f, vim = 0.f;
    const unsigned short* p = Bu + (size_t)chunk * LCHUNK * BATCH * 1024 + (size_t)b * 1024 + h;
    for (int j = 0; j < LCHUNK; ++j) {
        float br = bf2f(p[0]), bi = bf2f(p[512]);
        float nr = lre * vre - lim * vim + br;
        float ni = lre * vim + lim * vre + bi;
        vre = nr; vim = ni;
        p += BATCH * 1024;
    }
    car_re[chunk * NCHAIN + c] = vre;
    car_im[chunk * NCHAIN + c] = vim;
}

// ---------------- scan pass 2: combine chunk carries; emit final_state ----------------
__global__ void scan_combine(const float* __restrict__ car_re, const float* __restrict__ car_im,
                             const float* __restrict__ l64_re, const float* __restrict__ l64_im,
                             const float* __restrict__ h0_re, const float* __restrict__ h0_im,
                             float* __restrict__ cin_re, float* __restrict__ cin_im,
                             float* __restrict__ out_final, int interleave) {
    int c = blockIdx.x * blockDim.x + threadIdx.x;       // 0 .. 8191
    int h = c & 511;
    float lre = l64_re[h], lim = l64_im[h];
    float vre = h0_re[c], vim = h0_im[c];
    for (int k = 0; k < NCHUNK; ++k) {
        cin_re[k * NCHAIN + c] = vre;
        cin_im[k * NCHAIN + c] = vim;
        float cr = car_re[k * NCHAIN + c], ci = car_im[k * NCHAIN + c];
        float nr = lre * vre - lim * vim + cr;
        float ni = lre * vim + lim * vre + ci;
        vre = nr; vim = ni;
    }
    if (interleave) {                    // complex64 viewed as float32 pairs
        out_final[2 * c]     = vre;
        out_final[2 * c + 1] = vim;
    } else {                             // real-part-only layout
        out_final[c] = vre;
    }
}

// ---------------- scan pass 3: recompute with carry-in, write h bf16 IN-PLACE over Bu ----------------
__global__ void scan_apply(unsigned short* __restrict__ Bu,
                           const float* __restrict__ lam_re, const float* __restrict__ lam_im,
                           const float* __restrict__ cin_re, const float* __restrict__ cin_im) {
    int gid = blockIdx.x * blockDim.x + threadIdx.x;
    int chunk = gid >> 13;
    int c = gid & (NCHAIN - 1);
    int b = c >> 9, h = c & 511;
    float lre = lam_re[h], lim = lam_im[h];
    float vre = cin_re[chunk * NCHAIN + c], vim = cin_im[chunk * NCHAIN + c];
    unsigned short* p = Bu + (size_t)chunk * LCHUNK * BATCH * 1024 + (size_t)b * 1024 + h;
    for (int j = 0; j < LCHUNK; ++j) {
        float br = bf2f(p[0]), bi = bf2f(p[512]);
        float nr = lre * vre - lim * vim + br;
        float ni = lre * vim + lim * vre + bi;
        vre = nr; vim = ni;
        p[0]   = f2bf(vre);              // in-place: each element owned by exactly this thread
        p[512] = f2bf(vim);
        p += BATCH * 1024;
    }
}

// ---------------- launch ----------------
extern "C" void kernel_launch(void* const* d_in, const int* in_sizes, int n_in,
                              void* d_out, int out_size, void* d_ws, size_t ws_size,
                              hipStream_t stream) {
    const float* x        = (const float*)d_in[0];
    const float* h0_re    = (const float*)d_in[1];
    const float* h0_im    = (const float*)d_in[2];
    const float* nu_log   = (const float*)d_in[3];
    const float* theta_lg = (const float*)d_in[4];
    const float* B_re     = (const float*)d_in[5];
    const float* B_im     = (const float*)d_in[6];
    const float* C_re     = (const float*)d_in[7];
    const float* C_im     = (const float*)d_in[8];
    const float* D_vec    = (const float*)d_in[9];

    // workspace layout (~102 MB total)
    char* ws = (char*)d_ws;
    unsigned short* BuH  = (unsigned short*)(ws + 0);              // 64 MB  (M x 1024 bf16): Bu, then h in-place
    unsigned short* xb   = (unsigned short*)(ws + 67108864);       // 32 MB  (M x 512 bf16)
    unsigned short* Bs   = (unsigned short*)(ws + 100663296);      // 1 MB   (1024 x 512 bf16)
    unsigned short* C2   = (unsigned short*)(ws + 101711872);      // 1 MB   (512 x 1024 bf16)
    float* car_re        = (float*)(ws + 102760448);               // 1 MB
    float* car_im        = (float*)(ws + 103809024);               // 1 MB
    float* cin_re        = (float*)(ws + 104857600);               // 1 MB
    float* cin_im        = (float*)(ws + 105906176);               // 1 MB
    float* lam_re        = (float*)(ws + 106954752);
    float* lam_im        = (float*)(ws + 106956800);
    float* l64_re        = (float*)(ws + 106958848);
    float* l64_im        = (float*)(ws + 106960896);
    float* gam           = (float*)(ws + 106962944);

    // adaptive d_out layout: out_size = Y_ELEMS + {16384 interleaved | 8192 real-only}
    int fs_elems = out_size - Y_ELEMS;
    int interleave = (fs_elems == 8192) ? 0 : 1;
    if (fs_elems != 8192) fs_elems = 16384;
    float* out_final = (float*)d_out;
    float* y_out     = (float*)d_out + fs_elems;

    // 1. channel constants
    prep_kernel<<<2, 256, 0, stream>>>(nu_log, theta_lg, lam_re, lam_im, l64_re, l64_im, gam);
    // 2. operand conversions
    conv_B_kernel<<<(1024 * 512) / 256, 256, 0, stream>>>(B_re, B_im, gam, Bs);
    conv_C_kernel<<<(512 * 1024) / 256, 256, 0, stream>>>(C_re, C_im, C2);
    cast_x_kernel<<<(Y_ELEMS / 4) / 256, 256, 0, stream>>>((const float4*)x, xb, Y_ELEMS / 4);
    // 3. GEMM1: Bu = xb (M x 512) . Bs^T (1024 x 512) -> M x 1024 bf16
    {
        dim3 g(M_ROWS / 128, 1024 / 128);
        gemm_nt<0><<<g, 256, 0, stream>>>(xb, Bs, DMODEL, 1024, BuH, nullptr, nullptr, nullptr);
    }
    // 4. chunked scan over T (h overwrites Bu in-place)
    scan_partial<<<(NCHUNK * NCHAIN) / 256, 256, 0, stream>>>(BuH, lam_re, lam_im, car_re, car_im);
    scan_combine<<<NCHAIN / 256, 256, 0, stream>>>(car_re, car_im, l64_re, l64_im,
                                                   h0_re, h0_im, cin_re, cin_im, out_final, interleave);
    scan_apply<<<(NCHUNK * NCHAIN) / 256, 256, 0, stream>>>(BuH, lam_re, lam_im, cin_re, cin_im);
    // 5. GEMM2: y = h (M x 1024) . C2^T (512 x 1024) + Dv*x -> M x 512 fp32
    {
        dim3 g(M_ROWS / 128, 512 / 128);
        gemm_nt<1><<<g, 256, 0, stream>>>(BuH, C2, 1024, 512, nullptr, y_out, D_vec, x);
    }
}

// Round 3
// 291.034 us; speedup vs baseline: 1.0715x; 1.0715x over previous
//
#include <hip/hip_runtime.h>
#include <stdint.h>

// ---------------- types ----------------
typedef short shortx8 __attribute__((ext_vector_type(8)));
typedef float floatx4 __attribute__((ext_vector_type(4)));

#define T_LEN 2048
#define BATCH 16
#define DMODEL 512
#define HDIM 512
#define M_ROWS (T_LEN * BATCH)          // 32768
#define NCHUNK 32
#define LCHUNK 64                        // T per chunk
#define NCHAIN (BATCH * HDIM)            // 8192
#define Y_ELEMS (M_ROWS * DMODEL)        // 16777216

// ---------------- helpers ----------------
__device__ __forceinline__ unsigned short f2bf(float f) {
    union { float f; unsigned u; } v; v.f = f;
    unsigned r = (v.u + 0x7FFFu + ((v.u >> 16) & 1u)) >> 16;
    return (unsigned short)r;
}
__device__ __forceinline__ float bf2f(unsigned short u) {
    union { unsigned u; float f; } v; v.u = ((unsigned)u) << 16;
    return v.f;
}

// ---------------- prep: per-channel Lam, Lam^64, gamma ----------------
__global__ void prep_kernel(const float* __restrict__ nu_log, const float* __restrict__ th_log,
                            float* lam_re, float* lam_im, float* l64_re, float* l64_im, float* gam) {
    int h = blockIdx.x * blockDim.x + threadIdx.x;
    if (h >= HDIM) return;
    double nu  = exp((double)nu_log[h]);
    double th  = exp((double)th_log[h]);
    double mag = exp(-nu);
    double lre = mag * cos(th), lim = mag * sin(th);
    double g   = sqrt(1.0 - exp(-2.0 * nu));
    double zr = lre, zi = lim;
    for (int i = 0; i < 6; ++i) { double nr = zr*zr - zi*zi; zi = 2.0*zr*zi; zr = nr; }
    lam_re[h] = (float)lre; lam_im[h] = (float)lim;
    l64_re[h] = (float)zr;  l64_im[h] = (float)zi;
    gam[h] = (float)g;
}

// ---------------- merged operand conversion ----------------
// idx < 512K:  Bs_wide bf16 (2H x D): rows 0..511 = B_re*gamma, 512..1023 = B_im*gamma
// idx >= 512K: C2 bf16 (D x 2H): cols 0..511 = C_re, 512..1023 = -C_im
__global__ void conv_BC_kernel(const float* __restrict__ B_re, const float* __restrict__ B_im,
                               const float* __restrict__ gam,
                               const float* __restrict__ C_re, const float* __restrict__ C_im,
                               unsigned short* __restrict__ Bs, unsigned short* __restrict__ C2) {
    int idx = blockIdx.x * blockDim.x + threadIdx.x;     // 0 .. 1M-1
    if (idx < 524288) {
        int n = idx >> 9;        // /512
        int d = idx & 511;
        int h = n & 511;
        float v = (n < HDIM ? B_re[h * DMODEL + d] : B_im[h * DMODEL + d]) * gam[h];
        Bs[idx] = f2bf(v);
    } else {
        int i2 = idx - 524288;
        int d = i2 >> 10;        // /1024
        int k = i2 & 1023;
        float v = (k < HDIM) ? C_re[d * HDIM + k] : -C_im[d * HDIM + (k - HDIM)];
        C2[i2] = f2bf(v);
    }
}

// ---------------- cast x fp32 -> bf16 ----------------
__global__ void cast_x_kernel(const float4* __restrict__ x4, unsigned short* __restrict__ xb, int n4) {
    int i = blockIdx.x * blockDim.x + threadIdx.x;
    if (i >= n4) return;
    float4 v = x4[i];
    ushort4 u;
    u.x = f2bf(v.x); u.y = f2bf(v.y); u.z = f2bf(v.z); u.w = f2bf(v.w);
    *(ushort4*)(xb + (size_t)i * 4) = u;
}

// ---------------- NT GEMM, 128x128 tile, bf16 MFMA 16x16x32, XCD-swizzled grid ------
// A: M x K row-major bf16.  Bmat: N x K row-major bf16.  D[m][n] = sum_k A[m][k]*Bmat[n][k]
// 1-D grid; lgNB = log2(N/128).  Block mapping: xcd = L%8, bm = xcd*32 + slot>>lgNB,
// bn = slot & (NB-1) -> blocks co-resident on an XCD share a narrow bm window (A-tiles
// stay in that XCD's 4 MB L2; per-XCD working set ~2.6 MB).
// MODE 0: OutB[m*N+n] = bf16(acc)
// MODE 1: OutF[m*N+n] = acc + Dv[n]*Xf[m*N+n]
template <int MODE>
__global__ __launch_bounds__(256) void gemm_nt(const unsigned short* __restrict__ A,
                                               const unsigned short* __restrict__ Bmat,
                                               const int K, const int N, const int lgNB,
                                               unsigned short* __restrict__ OutB,
                                               float* __restrict__ OutF,
                                               const float* __restrict__ Dv,
                                               const float* __restrict__ Xf) {
    __shared__ unsigned short As[128 * 32];
    __shared__ unsigned short Bs[128 * 32];
    const int L = blockIdx.x;
    const int xcd = L & 7;
    const int slot = L >> 3;
    const int bn = slot & ((1 << lgNB) - 1);
    const int bm = xcd * 32 + (slot >> lgNB);
    const int tid = threadIdx.x;
    const int wv = tid >> 6, lane = tid & 63;
    const int wr = wv >> 1, wc = wv & 1;
    const int lrow = lane & 15, qq = lane >> 4;
    floatx4 acc[4][4] = {};

    const size_t rowA = (size_t)bm * 128, rowB = (size_t)bn * 128;
    for (int k0 = 0; k0 < K; k0 += 32) {
        // stage 128x32 A tile and B tile via async global->LDS, 16B/lane
        #pragma unroll
        for (int j = 0; j < 2; ++j) {
            int chunk = j * 256 + wv * 64 + lane;          // 0..511
            int r  = chunk >> 2;
            int cc = (chunk & 3) * 8;
            const unsigned short* ga = A    + (rowA + r) * (size_t)K + (k0 + cc);
            const unsigned short* gb = Bmat + (rowB + r) * (size_t)K + (k0 + cc);
            unsigned short* la = As + (size_t)(j * 256 + wv * 64) * 8;   // wave-uniform base
            unsigned short* lb = Bs + (size_t)(j * 256 + wv * 64) * 8;
            __builtin_amdgcn_global_load_lds((const __attribute__((address_space(1))) void*)ga,
                                             (__attribute__((address_space(3))) void*)la, 16, 0, 0);
            __builtin_amdgcn_global_load_lds((const __attribute__((address_space(1))) void*)gb,
                                             (__attribute__((address_space(3))) void*)lb, 16, 0, 0);
        }
        __syncthreads();
        shortx8 af[4], bf[4];
        #pragma unroll
        for (int mi = 0; mi < 4; ++mi)
            af[mi] = *(const shortx8*)&As[(wr * 64 + mi * 16 + lrow) * 32 + qq * 8];
        #pragma unroll
        for (int ni = 0; ni < 4; ++ni)
            bf[ni] = *(const shortx8*)&Bs[(wc * 64 + ni * 16 + lrow) * 32 + qq * 8];
        #pragma unroll
        for (int mi = 0; mi < 4; ++mi)
            #pragma unroll
            for (int ni = 0; ni < 4; ++ni)
                acc[mi][ni] = __builtin_amdgcn_mfma_f32_16x16x32_bf16(af[mi], bf[ni], acc[mi][ni], 0, 0, 0);
        __syncthreads();
    }

    // epilogue: D row = qq*4 + r, col = lrow   (m89/m91-verified C/D mapping)
    #pragma unroll
    for (int mi = 0; mi < 4; ++mi) {
        int mbase = bm * 128 + wr * 64 + mi * 16 + qq * 4;
        #pragma unroll
        for (int ni = 0; ni < 4; ++ni) {
            int n = bn * 128 + wc * 64 + ni * 16 + lrow;
            if (MODE == 0) {
                #pragma unroll
                for (int r = 0; r < 4; ++r)
                    OutB[(size_t)(mbase + r) * N + n] = f2bf(acc[mi][ni][r]);
            } else {
                float dv = Dv[n];
                #pragma unroll
                for (int r = 0; r < 4; ++r) {
                    size_t idx = (size_t)(mbase + r) * N + n;
                    OutF[idx] = acc[mi][ni][r] + dv * Xf[idx];
                }
            }
        }
    }
}

// ---------------- scan pass 1: per-chunk partial (zero init), 2 channels/thread -----
__global__ void scan_partial(const unsigned short* __restrict__ Bu,
                             const float* __restrict__ lam_re, const float* __restrict__ lam_im,
                             float* __restrict__ car_re, float* __restrict__ car_im) {
    int gid = blockIdx.x * blockDim.x + threadIdx.x;     // 0 .. 32*4096-1
    int chunk = gid >> 12;
    int idx = gid & 4095;
    int b = idx >> 8, hp = idx & 255;
    int h = hp * 2;
    float lr0 = lam_re[h], li0 = lam_im[h];
    float lr1 = lam_re[h + 1], li1 = lam_im[h + 1];
    float v0r = 0.f, v0i = 0.f, v1r = 0.f, v1i = 0.f;
    const unsigned short* p = Bu + (size_t)chunk * LCHUNK * BATCH * 1024 + (size_t)b * 1024 + h;
    for (int j = 0; j < LCHUNK; ++j) {
        unsigned rr = *(const unsigned*)p;
        unsigned ii = *(const unsigned*)(p + 512);
        float b0r = bf2f((unsigned short)rr), b1r = bf2f((unsigned short)(rr >> 16));
        float b0i = bf2f((unsigned short)ii), b1i = bf2f((unsigned short)(ii >> 16));
        float n0r = lr0 * v0r - li0 * v0i + b0r;
        float n0i = lr0 * v0i + li0 * v0r + b0i;
        float n1r = lr1 * v1r - li1 * v1i + b1r;
        float n1i = lr1 * v1i + li1 * v1r + b1i;
        v0r = n0r; v0i = n0i; v1r = n1r; v1i = n1i;
        p += BATCH * 1024;
    }
    int c = b * 512 + h;
    *(float2*)&car_re[chunk * NCHAIN + c] = make_float2(v0r, v1r);
    *(float2*)&car_im[chunk * NCHAIN + c] = make_float2(v0i, v1i);
}

// ---------------- scan pass 2: combine chunk carries; emit final_state ----------------
__global__ void scan_combine(const float* __restrict__ car_re, const float* __restrict__ car_im,
                             const float* __restrict__ l64_re, const float* __restrict__ l64_im,
                             const float* __restrict__ h0_re, const float* __restrict__ h0_im,
                             float* __restrict__ cin_re, float* __restrict__ cin_im,
                             float* __restrict__ out_final, int interleave) {
    int c = blockIdx.x * blockDim.x + threadIdx.x;       // 0 .. 8191
    int h = c & 511;
    float lre = l64_re[h], lim = l64_im[h];
    float vre = h0_re[c], vim = h0_im[c];
    for (int k = 0; k < NCHUNK; ++k) {
        cin_re[k * NCHAIN + c] = vre;
        cin_im[k * NCHAIN + c] = vim;
        float cr = car_re[k * NCHAIN + c], ci = car_im[k * NCHAIN + c];
        float nr = lre * vre - lim * vim + cr;
        float ni = lre * vim + lim * vre + ci;
        vre = nr; vim = ni;
    }
    if (interleave) {                    // complex64 viewed as float32 pairs
        out_final[2 * c]     = vre;
        out_final[2 * c + 1] = vim;
    } else {                             // real-part-only layout
        out_final[c] = vre;
    }
}

// ---------------- scan pass 3: recompute with carry-in, h bf16 in-place, 2 ch/thread --
__global__ void scan_apply(unsigned short* __restrict__ Bu,
                           const float* __restrict__ lam_re, const float* __restrict__ lam_im,
                           const float* __restrict__ cin_re, const float* __restrict__ cin_im) {
    int gid = blockIdx.x * blockDim.x + threadIdx.x;
    int chunk = gid >> 12;
    int idx = gid & 4095;
    int b = idx >> 8, hp = idx & 255;
    int h = hp * 2;
    int c = b * 512 + h;
    float lr0 = lam_re[h], li0 = lam_im[h];
    float lr1 = lam_re[h + 1], li1 = lam_im[h + 1];
    float2 cr = *(const float2*)&cin_re[chunk * NCHAIN + c];
    float2 ci = *(const float2*)&cin_im[chunk * NCHAIN + c];
    float v0r = cr.x, v0i = ci.x, v1r = cr.y, v1i = ci.y;
    unsigned short* p = Bu + (size_t)chunk * LCHUNK * BATCH * 1024 + (size_t)b * 1024 + h;
    for (int j = 0; j < LCHUNK; ++j) {
        unsigned rr = *(const unsigned*)p;
        unsigned ii = *(const unsigned*)(p + 512);
        float b0r = bf2f((unsigned short)rr), b1r = bf2f((unsigned short)(rr >> 16));
        float b0i = bf2f((unsigned short)ii), b1i = bf2f((unsigned short)(ii >> 16));
        float n0r = lr0 * v0r - li0 * v0i + b0r;
        float n0i = lr0 * v0i + li0 * v0r + b0i;
        float n1r = lr1 * v1r - li1 * v1i + b1r;
        float n1i = lr1 * v1i + li1 * v1r + b1i;
        v0r = n0r; v0i = n0i; v1r = n1r; v1i = n1i;
        *(unsigned*)p         = (unsigned)f2bf(v0r) | ((unsigned)f2bf(v1r) << 16);
        *(unsigned*)(p + 512) = (unsigned)f2bf(v0i) | ((unsigned)f2bf(v1i) << 16);
        p += BATCH * 1024;
    }
}

// ---------------- launch ----------------
extern "C" void kernel_launch(void* const* d_in, const int* in_sizes, int n_in,
                              void* d_out, int out_size, void* d_ws, size_t ws_size,
                              hipStream_t stream) {
    const float* x        = (const float*)d_in[0];
    const float* h0_re    = (const float*)d_in[1];
    const float* h0_im    = (const float*)d_in[2];
    const float* nu_log   = (const float*)d_in[3];
    const float* theta_lg = (const float*)d_in[4];
    const float* B_re     = (const float*)d_in[5];
    const float* B_im     = (const float*)d_in[6];
    const float* C_re     = (const float*)d_in[7];
    const float* C_im     = (const float*)d_in[8];
    const float* D_vec    = (const float*)d_in[9];

    // workspace layout (~102 MB total)
    char* ws = (char*)d_ws;
    unsigned short* BuH  = (unsigned short*)(ws + 0);              // 64 MB  (M x 1024 bf16): Bu, then h in-place
    unsigned short* xb   = (unsigned short*)(ws + 67108864);       // 32 MB  (M x 512 bf16)
    unsigned short* Bs   = (unsigned short*)(ws + 100663296);      // 1 MB   (1024 x 512 bf16)
    unsigned short* C2   = (unsigned short*)(ws + 101711872);      // 1 MB   (512 x 1024 bf16)
    float* car_re        = (float*)(ws + 102760448);               // 1 MB
    float* car_im        = (float*)(ws + 103809024);               // 1 MB
    float* cin_re        = (float*)(ws + 104857600);               // 1 MB
    float* cin_im        = (float*)(ws + 105906176);               // 1 MB
    float* lam_re        = (float*)(ws + 106954752);
    float* lam_im        = (float*)(ws + 106956800);
    float* l64_re        = (float*)(ws + 106958848);
    float* l64_im        = (float*)(ws + 106960896);
    float* gam           = (float*)(ws + 106962944);

    // adaptive d_out layout: out_size = Y_ELEMS + {16384 interleaved | 8192 real-only}
    int fs_elems = out_size - Y_ELEMS;
    int interleave = (fs_elems == 8192) ? 0 : 1;
    if (fs_elems != 8192) fs_elems = 16384;
    float* out_final = (float*)d_out;
    float* y_out     = (float*)d_out + fs_elems;

    // 1. channel constants
    prep_kernel<<<2, 256, 0, stream>>>(nu_log, theta_lg, lam_re, lam_im, l64_re, l64_im, gam);
    // 2. operand conversions (merged) + x cast
    conv_BC_kernel<<<(1048576) / 256, 256, 0, stream>>>(B_re, B_im, gam, C_re, C_im, Bs, C2);
    cast_x_kernel<<<(Y_ELEMS / 4) / 256, 256, 0, stream>>>((const float4*)x, xb, Y_ELEMS / 4);
    // 3. GEMM1: Bu = xb (M x 512) . Bs^T (1024 x 512) -> M x 1024 bf16
    gemm_nt<0><<<2048, 256, 0, stream>>>(xb, Bs, DMODEL, 1024, 3, BuH, nullptr, nullptr, nullptr);
    // 4. chunked scan over T (h overwrites Bu in-place)
    scan_partial<<<(NCHUNK * NCHAIN / 2) / 256, 256, 0, stream>>>(BuH, lam_re, lam_im, car_re, car_im);
    scan_combine<<<NCHAIN / 256, 256, 0, stream>>>(car_re, car_im, l64_re, l64_im,
                                                   h0_re, h0_im, cin_re, cin_im, out_final, interleave);
    scan_apply<<<(NCHUNK * NCHAIN / 2) / 256, 256, 0, stream>>>(BuH, lam_re, lam_im, cin_re, cin_im);
    // 5. GEMM2: y = h (M x 1024) . C2^T (512 x 1024) + Dv*x -> M x 512 fp32
    gemm_nt<1><<<1024, 256, 0, stream>>>(BuH, C2, 1024, 512, 2, nullptr, y_out, D_vec, x);
}

// Round 4
// 259.362 us; speedup vs baseline: 1.2024x; 1.1221x over previous
//
#include <hip/hip_runtime.h>
#include <stdint.h>

// ---------------- types ----------------
typedef short shortx8 __attribute__((ext_vector_type(8)));
typedef float floatx4 __attribute__((ext_vector_type(4)));

#define T_LEN 2048
#define BATCH 16
#define DMODEL 512
#define HDIM 512
#define M_ROWS (T_LEN * BATCH)          // 32768
#define NCHUNK 32
#define LCHUNK 64                        // T per chunk
#define NCHAIN (BATCH * HDIM)            // 8192
#define Y_ELEMS (M_ROWS * DMODEL)        // 16777216

// ---------------- helpers ----------------
__device__ __forceinline__ unsigned short f2bf(float f) {
    union { float f; unsigned u; } v; v.f = f;
    unsigned r = (v.u + 0x7FFFu + ((v.u >> 16) & 1u)) >> 16;
    return (unsigned short)r;
}
__device__ __forceinline__ float bf2f(unsigned short u) {
    union { unsigned u; float f; } v; v.u = ((unsigned)u) << 16;
    return v.f;
}

// ---------------- prep: per-channel Lam, Lam^64, gamma ----------------
__global__ void prep_kernel(const float* __restrict__ nu_log, const float* __restrict__ th_log,
                            float* lam_re, float* lam_im, float* l64_re, float* l64_im, float* gam) {
    int h = blockIdx.x * blockDim.x + threadIdx.x;
    if (h >= HDIM) return;
    double nu  = exp((double)nu_log[h]);
    double th  = exp((double)th_log[h]);
    double mag = exp(-nu);
    double lre = mag * cos(th), lim = mag * sin(th);
    double g   = sqrt(1.0 - exp(-2.0 * nu));
    double zr = lre, zi = lim;
    for (int i = 0; i < 6; ++i) { double nr = zr*zr - zi*zi; zi = 2.0*zr*zi; zr = nr; }
    lam_re[h] = (float)lre; lam_im[h] = (float)lim;
    l64_re[h] = (float)zr;  l64_im[h] = (float)zi;
    gam[h] = (float)g;
}

// ---------------- merged operand conversion ----------------
__global__ void conv_BC_kernel(const float* __restrict__ B_re, const float* __restrict__ B_im,
                               const float* __restrict__ gam,
                               const float* __restrict__ C_re, const float* __restrict__ C_im,
                               unsigned short* __restrict__ Bs, unsigned short* __restrict__ C2) {
    int idx = blockIdx.x * blockDim.x + threadIdx.x;     // 0 .. 1M-1
    if (idx < 524288) {
        int n = idx >> 9;        // /512
        int d = idx & 511;
        int h = n & 511;
        float v = (n < HDIM ? B_re[h * DMODEL + d] : B_im[h * DMODEL + d]) * gam[h];
        Bs[idx] = f2bf(v);
    } else {
        int i2 = idx - 524288;
        int d = i2 >> 10;        // /1024
        int k = i2 & 1023;
        float v = (k < HDIM) ? C_re[d * HDIM + k] : -C_im[d * HDIM + (k - HDIM)];
        C2[i2] = f2bf(v);
    }
}

// ---------------- cast x fp32 -> bf16 ----------------
__global__ void cast_x_kernel(const float4* __restrict__ x4, unsigned short* __restrict__ xb, int n4) {
    int i = blockIdx.x * blockDim.x + threadIdx.x;
    if (i >= n4) return;
    float4 v = x4[i];
    ushort4 u;
    u.x = f2bf(v.x); u.y = f2bf(v.y); u.z = f2bf(v.z); u.w = f2bf(v.w);
    *(ushort4*)(xb + (size_t)i * 4) = u;
}

// ---------------- NT GEMM, 128x128 tile, BK=64, bf16 MFMA 16x16x32 ----------------
// A: M x K row-major bf16.  Bmat: N x K row-major bf16.  D[m][n] = sum_k A[m][k]*Bmat[n][k]
// LDS tiles 128x64 with XOR-swizzled 16B column chunks (c16 ^= r&7) to kill bank
// conflicts; swizzle is applied to the GLOBAL source column so global_load_lds's
// contiguous lane-scatter (base + lane*16B) is preserved.
// XCD swizzle: xcd = L%8, bm = xcd*32 + slot>>lgNB, bn = slot&(NB-1).
// MODE 0: OutB[m*N+n] = bf16(acc)
// MODE 1: OutF[m*N+n] = acc + Dv[n]*bf2f(Xb[m*N+n])
template <int MODE>
__global__ __launch_bounds__(256, 4) void gemm_nt(const unsigned short* __restrict__ A,
                                                  const unsigned short* __restrict__ Bmat,
                                                  const int K, const int N, const int lgNB,
                                                  unsigned short* __restrict__ OutB,
                                                  float* __restrict__ OutF,
                                                  const float* __restrict__ Dv,
                                                  const unsigned short* __restrict__ Xb) {
    __shared__ unsigned short As[128 * 64];
    __shared__ unsigned short Bs[128 * 64];
    const int L = blockIdx.x;
    const int xcd = L & 7;
    const int slot = L >> 3;
    const int bn = slot & ((1 << lgNB) - 1);
    const int bm = xcd * 32 + (slot >> lgNB);
    const int tid = threadIdx.x;
    const int wv = tid >> 6, lane = tid & 63;
    const int wr = wv >> 1, wc = wv & 1;
    const int lrow = lane & 15, qq = lane >> 4;
    floatx4 acc[4][4] = {};

    const size_t rowA = (size_t)bm * 128, rowB = (size_t)bn * 128;
    for (int k0 = 0; k0 < K; k0 += 64) {
        // stage 128x64 tiles: 1024 16B-chunks per matrix, 4 per thread
        #pragma unroll
        for (int j = 0; j < 4; ++j) {
            int ch  = j * 256 + wv * 64 + lane;            // 0..1023
            int r   = ch >> 3;                             // row 0..127
            int c16 = ch & 7;                              // LDS 16B-col
            int g16 = c16 ^ (r & 7);                       // swizzled global 16B-col
            const unsigned short* ga = A    + (rowA + r) * (size_t)K + (k0 + g16 * 8);
            const unsigned short* gb = Bmat + (rowB + r) * (size_t)K + (k0 + g16 * 8);
            unsigned short* la = As + (size_t)(j * 256 + wv * 64) * 8;   // wave-uniform base
            unsigned short* lb = Bs + (size_t)(j * 256 + wv * 64) * 8;
            __builtin_amdgcn_global_load_lds((const __attribute__((address_space(1))) void*)ga,
                                             (__attribute__((address_space(3))) void*)la, 16, 0, 0);
            __builtin_amdgcn_global_load_lds((const __attribute__((address_space(1))) void*)gb,
                                             (__attribute__((address_space(3))) void*)lb, 16, 0, 0);
        }
        __syncthreads();
        #pragma unroll
        for (int s = 0; s < 2; ++s) {                      // two k-substeps of 32
            shortx8 af[4], bf[4];
            #pragma unroll
            for (int mi = 0; mi < 4; ++mi) {
                int row = wr * 64 + mi * 16 + lrow;
                int c16 = (s * 4 + qq) ^ (row & 7);
                af[mi] = *(const shortx8*)&As[row * 64 + c16 * 8];
            }
            #pragma unroll
            for (int ni = 0; ni < 4; ++ni) {
                int row = wc * 64 + ni * 16 + lrow;
                int c16 = (s * 4 + qq) ^ (row & 7);
                bf[ni] = *(const shortx8*)&Bs[row * 64 + c16 * 8];
            }
            #pragma unroll
            for (int mi = 0; mi < 4; ++mi)
                #pragma unroll
                for (int ni = 0; ni < 4; ++ni)
                    acc[mi][ni] = __builtin_amdgcn_mfma_f32_16x16x32_bf16(af[mi], bf[ni], acc[mi][ni], 0, 0, 0);
        }
        __syncthreads();
    }

    // epilogue: D row = qq*4 + r, col = lrow   (m89/m91-verified C/D mapping)
    #pragma unroll
    for (int mi = 0; mi < 4; ++mi) {
        int mbase = bm * 128 + wr * 64 + mi * 16 + qq * 4;
        #pragma unroll
        for (int ni = 0; ni < 4; ++ni) {
            int n = bn * 128 + wc * 64 + ni * 16 + lrow;
            if (MODE == 0) {
                #pragma unroll
                for (int r = 0; r < 4; ++r)
                    OutB[(size_t)(mbase + r) * N + n] = f2bf(acc[mi][ni][r]);
            } else {
                float dv = Dv[n];
                #pragma unroll
                for (int r = 0; r < 4; ++r) {
                    size_t idx = (size_t)(mbase + r) * N + n;
                    OutF[idx] = acc[mi][ni][r] + dv * bf2f(Xb[idx]);
                }
            }
        }
    }
}

// ---------------- scan pass 1: per-chunk partial (zero init), 2 channels/thread -----
__global__ void scan_partial(const unsigned short* __restrict__ Bu,
                             const float* __restrict__ lam_re, const float* __restrict__ lam_im,
                             float* __restrict__ car_re, float* __restrict__ car_im) {
    int gid = blockIdx.x * blockDim.x + threadIdx.x;     // 0 .. 32*4096-1
    int chunk = gid >> 12;
    int idx = gid & 4095;
    int b = idx >> 8, hp = idx & 255;
    int h = hp * 2;
    float lr0 = lam_re[h], li0 = lam_im[h];
    float lr1 = lam_re[h + 1], li1 = lam_im[h + 1];
    float v0r = 0.f, v0i = 0.f, v1r = 0.f, v1i = 0.f;
    const unsigned short* p = Bu + (size_t)chunk * LCHUNK * BATCH * 1024 + (size_t)b * 1024 + h;
    for (int j = 0; j < LCHUNK; ++j) {
        unsigned rr = *(const unsigned*)p;
        unsigned ii = *(const unsigned*)(p + 512);
        float b0r = bf2f((unsigned short)rr), b1r = bf2f((unsigned short)(rr >> 16));
        float b0i = bf2f((unsigned short)ii), b1i = bf2f((unsigned short)(ii >> 16));
        float n0r = lr0 * v0r - li0 * v0i + b0r;
        float n0i = lr0 * v0i + li0 * v0r + b0i;
        float n1r = lr1 * v1r - li1 * v1i + b1r;
        float n1i = lr1 * v1i + li1 * v1r + b1i;
        v0r = n0r; v0i = n0i; v1r = n1r; v1i = n1i;
        p += BATCH * 1024;
    }
    int c = b * 512 + h;
    *(float2*)&car_re[chunk * NCHAIN + c] = make_float2(v0r, v1r);
    *(float2*)&car_im[chunk * NCHAIN + c] = make_float2(v0i, v1i);
}

// ---------------- scan pass 2 (fused combine+apply): each chunk-block computes its own
// carry prefix from car (<=31 steps, block-uniform count), then streams 64 steps
// in-place over Bu; chunk 31 additionally writes final_state. ----------------
__global__ void scan_apply(unsigned short* __restrict__ Bu,
                           const float* __restrict__ lam_re, const float* __restrict__ lam_im,
                           const float* __restrict__ l64_re, const float* __restrict__ l64_im,
                           const float* __restrict__ h0_re, const float* __restrict__ h0_im,
                           const float* __restrict__ car_re, const float* __restrict__ car_im,
                           float* __restrict__ out_final, int interleave) {
    int gid = blockIdx.x * blockDim.x + threadIdx.x;
    int chunk = gid >> 12;           // block-uniform
    int idx = gid & 4095;
    int b = idx >> 8, hp = idx & 255;
    int h = hp * 2;
    int c = b * 512 + h;
    // carry-in: h0 advanced through preceding chunks via lam^64
    float L0r = l64_re[h], L0i = l64_im[h];
    float L1r = l64_re[h + 1], L1i = l64_im[h + 1];
    float v0r = h0_re[c], v0i = h0_im[c];
    float v1r = h0_re[c + 1], v1i = h0_im[c + 1];
    for (int k = 0; k < chunk; ++k) {
        float2 crr = *(const float2*)&car_re[k * NCHAIN + c];
        float2 cii = *(const float2*)&car_im[k * NCHAIN + c];
        float n0r = L0r * v0r - L0i * v0i + crr.x;
        float n0i = L0r * v0i + L0i * v0r + cii.x;
        float n1r = L1r * v1r - L1i * v1i + crr.y;
        float n1i = L1r * v1i + L1i * v1r + cii.y;
        v0r = n0r; v0i = n0i; v1r = n1r; v1i = n1i;
    }
    // main 64-step streaming recurrence, h overwrites Bu in-place
    float lr0 = lam_re[h], li0 = lam_im[h];
    float lr1 = lam_re[h + 1], li1 = lam_im[h + 1];
    unsigned short* p = Bu + (size_t)chunk * LCHUNK * BATCH * 1024 + (size_t)b * 1024 + h;
    for (int j = 0; j < LCHUNK; ++j) {
        unsigned rr = *(const unsigned*)p;
        unsigned ii = *(const unsigned*)(p + 512);
        float b0r = bf2f((unsigned short)rr), b1r = bf2f((unsigned short)(rr >> 16));
        float b0i = bf2f((unsigned short)ii), b1i = bf2f((unsigned short)(ii >> 16));
        float n0r = lr0 * v0r - li0 * v0i + b0r;
        float n0i = lr0 * v0i + li0 * v0r + b0i;
        float n1r = lr1 * v1r - li1 * v1i + b1r;
        float n1i = lr1 * v1i + li1 * v1r + b1i;
        v0r = n0r; v0i = n0i; v1r = n1r; v1i = n1i;
        *(unsigned*)p         = (unsigned)f2bf(v0r) | ((unsigned)f2bf(v1r) << 16);
        *(unsigned*)(p + 512) = (unsigned)f2bf(v0i) | ((unsigned)f2bf(v1i) << 16);
        p += BATCH * 1024;
    }
    if (chunk == NCHUNK - 1) {       // final_state = h[T-1]
        if (interleave) {
            out_final[2 * c]     = v0r;
            out_final[2 * c + 1] = v0i;
            out_final[2 * c + 2] = v1r;
            out_final[2 * c + 3] = v1i;
        } else {
            out_final[c]     = v0r;
            out_final[c + 1] = v1r;
        }
    }
}

// ---------------- launch ----------------
extern "C" void kernel_launch(void* const* d_in, const int* in_sizes, int n_in,
                              void* d_out, int out_size, void* d_ws, size_t ws_size,
                              hipStream_t stream) {
    const float* x        = (const float*)d_in[0];
    const float* h0_re    = (const float*)d_in[1];
    const float* h0_im    = (const float*)d_in[2];
    const float* nu_log   = (const float*)d_in[3];
    const float* theta_lg = (const float*)d_in[4];
    const float* B_re     = (const float*)d_in[5];
    const float* B_im     = (const float*)d_in[6];
    const float* C_re     = (const float*)d_in[7];
    const float* C_im     = (const float*)d_in[8];
    const float* D_vec    = (const float*)d_in[9];

    // workspace layout (~102 MB total)
    char* ws = (char*)d_ws;
    unsigned short* BuH  = (unsigned short*)(ws + 0);              // 64 MB  (M x 1024 bf16): Bu, then h in-place
    unsigned short* xb   = (unsigned short*)(ws + 67108864);       // 32 MB  (M x 512 bf16)
    unsigned short* Bs   = (unsigned short*)(ws + 100663296);      // 1 MB   (1024 x 512 bf16)
    unsigned short* C2   = (unsigned short*)(ws + 101711872);      // 1 MB   (512 x 1024 bf16)
    float* car_re        = (float*)(ws + 102760448);               // 1 MB
    float* car_im        = (float*)(ws + 103809024);               // 1 MB
    float* lam_re        = (float*)(ws + 104857600);
    float* lam_im        = (float*)(ws + 104859648);
    float* l64_re        = (float*)(ws + 104861696);
    float* l64_im        = (float*)(ws + 104863744);
    float* gam           = (float*)(ws + 104865792);

    // adaptive d_out layout: out_size = Y_ELEMS + {16384 interleaved | 8192 real-only}
    int fs_elems = out_size - Y_ELEMS;
    int interleave = (fs_elems == 8192) ? 0 : 1;
    if (fs_elems != 8192) fs_elems = 16384;
    float* out_final = (float*)d_out;
    float* y_out     = (float*)d_out + fs_elems;

    // 1. channel constants
    prep_kernel<<<2, 256, 0, stream>>>(nu_log, theta_lg, lam_re, lam_im, l64_re, l64_im, gam);
    // 2. operand conversions (merged) + x cast
    conv_BC_kernel<<<(1048576) / 256, 256, 0, stream>>>(B_re, B_im, gam, C_re, C_im, Bs, C2);
    cast_x_kernel<<<(Y_ELEMS / 4) / 256, 256, 0, stream>>>((const float4*)x, xb, Y_ELEMS / 4);
    // 3. GEMM1: Bu = xb (M x 512) . Bs^T (1024 x 512) -> M x 1024 bf16
    gemm_nt<0><<<2048, 256, 0, stream>>>(xb, Bs, DMODEL, 1024, 3, BuH, nullptr, nullptr, nullptr);
    // 4. chunked scan over T (partial -> fused prefix+apply, h overwrites Bu in-place)
    scan_partial<<<(NCHUNK * NCHAIN / 2) / 256, 256, 0, stream>>>(BuH, lam_re, lam_im, car_re, car_im);
    scan_apply<<<(NCHUNK * NCHAIN / 2) / 256, 256, 0, stream>>>(BuH, lam_re, lam_im, l64_re, l64_im,
                                                                h0_re, h0_im, car_re, car_im,
                                                                out_final, interleave);
    // 5. GEMM2: y = h (M x 1024) . C2^T (512 x 1024) + Dv*xb -> M x 512 fp32
    gemm_nt<1><<<1024, 256, 0, stream>>>(BuH, C2, 1024, 512, 2, nullptr, y_out, D_vec, xb);
}